// Round 3
// baseline (231.420 us; speedup 1.0000x reference)
//
#include <hip/hip_runtime.h>
#include <math.h>

// Problem constants (N,C,H,W,D) = (64, 3, 256, 256, 512)
#define N_B 64
#define C_CH 3
#define H_IMG 256
#define W_IMG 256
#define D_FEAT 512

#define OUT_OFF_GRID   12582912
#define OUT_OFF_MATRIX 20971520
#define OUT_OFF_AFFINE 20971904

// LDS staging buffer geometry for the warp kernel
#define L0_STRIDE 68
#define L0_ROWS   68
#define L1_STRIDE 40
#define L1_ROWS   40

// ------------------------------------------------------------------
// Kernel 1: per-batch linear head -> affine matrix + level
// ------------------------------------------------------------------
__global__ void params_kernel(const float* __restrict__ features,
                              const float* __restrict__ lin_w,
                              const float* __restrict__ lin_b,
                              float* __restrict__ out_matrix,
                              float* __restrict__ out_affine,
                              float* __restrict__ ws_params)
{
    const int n = blockIdx.x;
    const int t = threadIdx.x;
    const float* f = features + n * D_FEAT;
    float f0 = f[t];
    float f1 = f[t + 256];
    float a0 = f0 * lin_w[0 * D_FEAT + t] + f1 * lin_w[0 * D_FEAT + t + 256];
    float a1 = f0 * lin_w[1 * D_FEAT + t] + f1 * lin_w[1 * D_FEAT + t + 256];
    float a2 = f0 * lin_w[2 * D_FEAT + t] + f1 * lin_w[2 * D_FEAT + t + 256];
    float a3 = f0 * lin_w[3 * D_FEAT + t] + f1 * lin_w[3 * D_FEAT + t + 256];

    __shared__ float red[4][256];
    red[0][t] = a0; red[1][t] = a1; red[2][t] = a2; red[3][t] = a3;
    __syncthreads();
    for (int s = 128; s > 0; s >>= 1) {
        if (t < s) {
            red[0][t] += red[0][t + s];
            red[1][t] += red[1][t + s];
            red[2][t] += red[2][t + s];
            red[3][t] += red[3][t + s];
        }
        __syncthreads();
    }
    if (t == 0) {
        float p0 = red[0][0] + lin_b[0];
        float p1 = red[1][0] + lin_b[1];
        float p2 = red[2][0] + lin_b[2];
        float p3 = red[3][0] + lin_b[3];
        float rot   = tanhf(p0) * 3.14159265358979323846f;
        float scale = expf(p1);
        float c = cosf(rot), s = sinf(rot);
        float m00 = scale * c, m01 = -scale * s, m02 = p2;
        float m10 = scale * s, m11 =  scale * c, m12 = p3;
        out_matrix[n * 6 + 0] = m00;
        out_matrix[n * 6 + 1] = m01;
        out_matrix[n * 6 + 2] = m02;
        out_matrix[n * 6 + 3] = m10;
        out_matrix[n * 6 + 4] = m11;
        out_matrix[n * 6 + 5] = m12;
        out_affine[n * 4 + 0] = rot;
        out_affine[n * 4 + 1] = scale;
        out_affine[n * 4 + 2] = p2;
        out_affine[n * 4 + 3] = p3;
        // affine grid => Jacobian norm is exactly `scale` in both directions
        float lv = log2f(fmaxf(scale, 1.0f));
        lv = fminf(fmaxf(lv, 0.0f), 2.5f);
        ws_params[n * 8 + 0] = m00;
        ws_params[n * 8 + 1] = m01;
        ws_params[n * 8 + 2] = m02;
        ws_params[n * 8 + 3] = m10;
        ws_params[n * 8 + 4] = m11;
        ws_params[n * 8 + 5] = m12;
        ws_params[n * 8 + 6] = lv;
        ws_params[n * 8 + 7] = 0.0f;
    }
}

// ------------------------------------------------------------------
// Kernel 2: depthwise 4x4 binomial blur, reflect (1,2), stride 2.
// 4 outputs per thread: 2 aligned float4 + 2 scalars per source row.
// ------------------------------------------------------------------
template<int Hs, int Ws>
__global__ void down_kernel(const float* __restrict__ src, float* __restrict__ dst)
{
    constexpr int Hd = Hs / 2, Wd = Ws / 2;
    constexpr int QUADS = Wd / 4;

    const int idx = blockIdx.x * blockDim.x + threadIdx.x;
    const int t   = idx & (QUADS - 1);
    const int i   = (idx / QUADS) & (Hd - 1);
    const int nc  = idx / (QUADS * Hd);

    const float* __restrict__ s = src + (size_t)nc * Hs * Ws;

    int r[4];
#pragma unroll
    for (int a = 0; a < 4; a++) {
        int q = 2 * i + a - 1;
        if (q < 0) q = -q;
        if (q >= Hs) q = 2 * Hs - 2 - q;
        r[a] = q;
    }
    const int c8 = 8 * t;
    const int li = (t > 0)         ? c8 - 1 : 1;       // reflect -1 -> 1
    const int ri = (t < QUADS - 1) ? c8 + 8 : Ws - 2;  // reflect Ws -> Ws-2

    const float k0 = 0.125f, k1 = 0.375f;
    const float kr[4] = {0.125f, 0.375f, 0.375f, 0.125f};

    float acc0 = 0.f, acc1 = 0.f, acc2 = 0.f, acc3 = 0.f;
#pragma unroll
    for (int a = 0; a < 4; a++) {
        const float* row = s + (size_t)r[a] * Ws;
        float4 A = *(const float4*)(row + c8);
        float4 B = *(const float4*)(row + c8 + 4);
        float L = row[li];
        float R = row[ri];
        float h0 = k0 * L   + k1 * A.x + k1 * A.y + k0 * A.z;
        float h1 = k0 * A.y + k1 * A.z + k1 * A.w + k0 * B.x;
        float h2 = k0 * A.w + k1 * B.x + k1 * B.y + k0 * B.z;
        float h3 = k0 * B.y + k1 * B.z + k1 * B.w + k0 * R;
        acc0 += kr[a] * h0;
        acc1 += kr[a] * h1;
        acc2 += kr[a] * h2;
        acc3 += kr[a] * h3;
    }
    float4* d4 = (float4*)(dst + (size_t)nc * Hd * Wd + (size_t)i * Wd + 4 * t);
    *d4 = make_float4(acc0, acc1, acc2, acc3);
}

// ------------------------------------------------------------------
// Kernel 3 helpers
// ------------------------------------------------------------------
__device__ __forceinline__ const float* lvl_ptr(int l, const float* img,
                                                const float* p1, const float* p2,
                                                const float* p3)
{
    return (l == 0) ? img : ((l == 1) ? p1 : ((l == 2) ? p2 : p3));
}

__device__ __forceinline__ void sample_level_direct(const float* __restrict__ p, int n, int l,
                                                    float X, float Y, float out[3])
{
    const int Wl = W_IMG >> l;
    const int Hl = H_IMG >> l;
    float x = (X + 1.0f) * (0.5f * (float)Wl) - 0.5f;
    float y = (Y + 1.0f) * (0.5f * (float)Hl) - 0.5f;
    float x0f = floorf(x), y0f = floorf(y);
    float tx = x - x0f, ty = y - y0f;
    int x0 = (int)x0f, y0 = (int)y0f;
    int x0i = min(max(x0,     0), Wl - 1);
    int x1i = min(max(x0 + 1, 0), Wl - 1);
    int y0i = min(max(y0,     0), Hl - 1);
    int y1i = min(max(y0 + 1, 0), Hl - 1);
    float w00 = (1.0f - tx) * (1.0f - ty);
    float w01 = tx * (1.0f - ty);
    float w10 = (1.0f - tx) * ty;
    float w11 = tx * ty;
    const float* base = p + (size_t)n * C_CH * Hl * Wl;
#pragma unroll
    for (int c = 0; c < C_CH; c++) {
        const float* pc = base + (size_t)c * Hl * Wl;
        out[c] = w00 * pc[y0i * Wl + x0i] + w01 * pc[y0i * Wl + x1i]
               + w10 * pc[y1i * Wl + x0i] + w11 * pc[y1i * Wl + x1i];
    }
}

// bbox of the bilinear footprint of a 32x8 tile at level l (block-uniform)
__device__ __forceinline__ void tile_bbox(int l, int w0, int h0,
                                          float m00, float m01, float m02,
                                          float m10, float m11, float m12,
                                          int& bx0, int& by0, int& bw, int& bh)
{
    const int Wl = W_IMG >> l;
    const int Hl = H_IMG >> l;
    float gx0 = ((float)w0 + 0.5f)  * (2.0f / W_IMG) - 1.0f;
    float gx1 = ((float)w0 + 31.5f) * (2.0f / W_IMG) - 1.0f;
    float gy0 = ((float)h0 + 0.5f)  * (2.0f / H_IMG) - 1.0f;
    float gy1 = ((float)h0 + 7.5f)  * (2.0f / H_IMG) - 1.0f;

    float X00 = m00 * gx0 + m01 * gy0 + m02;
    float X10 = m00 * gx1 + m01 * gy0 + m02;
    float X01 = m00 * gx0 + m01 * gy1 + m02;
    float X11 = m00 * gx1 + m01 * gy1 + m02;
    float Y00 = m10 * gx0 + m11 * gy0 + m12;
    float Y10 = m10 * gx1 + m11 * gy0 + m12;
    float Y01 = m10 * gx0 + m11 * gy1 + m12;
    float Y11 = m10 * gx1 + m11 * gy1 + m12;

    float hw = 0.5f * (float)Wl, hh = 0.5f * (float)Hl;
    float xmin = fminf(fminf(X00, X10), fminf(X01, X11)) * hw + hw - 0.5f;
    float xmax = fmaxf(fmaxf(X00, X10), fmaxf(X01, X11)) * hw + hw - 0.5f;
    float ymin = fminf(fminf(Y00, Y10), fminf(Y01, Y11)) * hh + hh - 0.5f;
    float ymax = fmaxf(fmaxf(Y00, Y10), fmaxf(Y01, Y11)) * hh + hh - 0.5f;

    int ix0 = min(max((int)floorf(xmin), 0), Wl - 1);
    int ix1 = min(max((int)floorf(xmax) + 1, 0), Wl - 1);
    int iy0 = min(max((int)floorf(ymin), 0), Hl - 1);
    int iy1 = min(max((int)floorf(ymax) + 1, 0), Hl - 1);
    bx0 = ix0; by0 = iy0; bw = ix1 - ix0 + 1; bh = iy1 - iy0 + 1;
}

// per-lane bilinear tap setup at level l, LDS-relative
__device__ __forceinline__ void tap_setup(int l, float X, float Y, int bx0, int by0,
                                          int stride, int& i00, int& i01, int& i10, int& i11,
                                          float& w00, float& w01, float& w10, float& w11)
{
    const int Wl = W_IMG >> l;
    const int Hl = H_IMG >> l;
    float x = (X + 1.0f) * (0.5f * (float)Wl) - 0.5f;
    float y = (Y + 1.0f) * (0.5f * (float)Hl) - 0.5f;
    float x0f = floorf(x), y0f = floorf(y);
    float tx = x - x0f, ty = y - y0f;
    int x0 = (int)x0f, y0 = (int)y0f;
    int x0i = min(max(x0,     0), Wl - 1) - bx0;
    int x1i = min(max(x0 + 1, 0), Wl - 1) - bx0;
    int y0i = min(max(y0,     0), Hl - 1) - by0;
    int y1i = min(max(y0 + 1, 0), Hl - 1) - by0;
    i00 = y0i * stride + x0i;
    i01 = y0i * stride + x1i;
    i10 = y1i * stride + x0i;
    i11 = y1i * stride + x1i;
    w00 = (1.0f - tx) * (1.0f - ty);
    w01 = tx * (1.0f - ty);
    w10 = (1.0f - tx) * ty;
    w11 = tx * ty;
}

__global__ void warp_kernel(const float* __restrict__ img,
                            const float* __restrict__ pyr1,
                            const float* __restrict__ pyr2,
                            const float* __restrict__ pyr3,
                            const float* __restrict__ ws_params,
                            float* __restrict__ out,
                            float* __restrict__ gridOut)
{
    __shared__ float lds0[L0_ROWS * L0_STRIDE];
    __shared__ float lds1[L1_ROWS * L1_STRIDE];

    const int n = blockIdx.y;
    const int tile = blockIdx.x;
    const int tid = threadIdx.x;
    const int w0 = (tile & 7) << 5;
    const int h0 = (tile >> 3) << 3;
    const int w = w0 + (tid & 31);
    const int h = h0 + (tid >> 5);

    const float* P = ws_params + n * 8;
    float m00 = P[0], m01 = P[1], m02 = P[2];
    float m10 = P[3], m11 = P[4], m12 = P[5];
    float lv  = P[6];

    float gx = ((float)w + 0.5f) * (2.0f / (float)W_IMG) - 1.0f;
    float gy = ((float)h + 0.5f) * (2.0f / (float)H_IMG) - 1.0f;
    float X = m00 * gx + m01 * gy + m02;
    float Y = m10 * gx + m11 * gy + m12;

    float2* g2 = (float2*)gridOut;
    g2[(size_t)(n * H_IMG + h) * W_IMG + w] = make_float2(X, Y);

    int   l0   = (int)lv;
    float frac = lv - (float)l0;
    const bool hasL1 = (frac > 0.0f);      // block-uniform

    // block-uniform bboxes
    int bx0_0, by0_0, bw_0, bh_0;
    tile_bbox(l0, w0, h0, m00, m01, m02, m10, m11, m12, bx0_0, by0_0, bw_0, bh_0);
    int bx0_1 = 0, by0_1 = 0, bw_1 = 1, bh_1 = 1;
    if (hasL1)
        tile_bbox(l0 + 1, w0, h0, m00, m01, m02, m10, m11, m12, bx0_1, by0_1, bw_1, bh_1);

    bool ldsOK = (bw_0 <= L0_STRIDE) && (bh_0 <= L0_ROWS) &&
                 (!hasL1 || ((bw_1 <= L1_STRIDE) && (bh_1 <= L1_ROWS)));

    size_t obase = ((size_t)n * C_CH * H_IMG + h) * W_IMG + w;

    if (!ldsOK) {   // pathological scale: direct global sampling (block-uniform)
        float c0[3];
        sample_level_direct(lvl_ptr(l0, img, pyr1, pyr2, pyr3), n, l0, X, Y, c0);
        float r0, r1, r2;
        if (hasL1) {
            float c1[3];
            sample_level_direct(lvl_ptr(l0 + 1, img, pyr1, pyr2, pyr3), n, l0 + 1, X, Y, c1);
            float wA = 1.0f - frac;
            r0 = wA * c0[0] + frac * c1[0];
            r1 = wA * c0[1] + frac * c1[1];
            r2 = wA * c0[2] + frac * c1[2];
        } else {
            r0 = c0[0]; r1 = c0[1]; r2 = c0[2];
        }
        out[obase]                             = r0;
        out[obase + (size_t)H_IMG * W_IMG]     = r1;
        out[obase + (size_t)2 * H_IMG * W_IMG] = r2;
        return;
    }

    // per-lane tap setup (LDS-relative)
    int i00, i01, i10, i11;  float w00, w01, w10, w11;
    tap_setup(l0, X, Y, bx0_0, by0_0, L0_STRIDE, i00, i01, i10, i11, w00, w01, w10, w11);
    int j00 = 0, j01 = 0, j10 = 0, j11 = 0;  float u00 = 0, u01 = 0, u10 = 0, u11 = 0;
    if (hasL1)
        tap_setup(l0 + 1, X, Y, bx0_1, by0_1, L1_STRIDE, j00, j01, j10, j11, u00, u01, u10, u11);

    const int Wl0 = W_IMG >> l0, Hl0 = H_IMG >> l0;
    const int Wl1 = W_IMG >> (l0 + 1), Hl1 = H_IMG >> (l0 + 1);
    const float* base0 = lvl_ptr(l0, img, pyr1, pyr2, pyr3) + (size_t)n * C_CH * Hl0 * Wl0;
    const float* base1 = hasL1 ? lvl_ptr(l0 + 1, img, pyr1, pyr2, pyr3) + (size_t)n * C_CH * Hl1 * Wl1
                               : base0;

    const int lane = tid & 63;
    const int rgrp = tid >> 6;   // 0..3

    float res[3];
#pragma unroll
    for (int c = 0; c < C_CH; c++) {
        // stage level l0 channel c (coalesced rows)
        {
            const float* plane = base0 + (size_t)c * Hl0 * Wl0;
            for (int r = rgrp; r < bh_0; r += 4) {
                const float* srow = plane + (size_t)(by0_0 + r) * Wl0 + bx0_0;
                float* lrow = lds0 + r * L0_STRIDE;
                if (lane < bw_0)      lrow[lane]      = srow[lane];
                if (lane + 64 < bw_0) lrow[lane + 64] = srow[lane + 64];
            }
        }
        if (hasL1) {
            const float* plane = base1 + (size_t)c * Hl1 * Wl1;
            for (int r = rgrp; r < bh_1; r += 4) {
                const float* srow = plane + (size_t)(by0_1 + r) * Wl1 + bx0_1;
                float* lrow = lds1 + r * L1_STRIDE;
                if (lane < bw_1) lrow[lane] = srow[lane];
            }
        }
        __syncthreads();

        float v = w00 * lds0[i00] + w01 * lds0[i01] + w10 * lds0[i10] + w11 * lds0[i11];
        if (hasL1) {
            float u = u00 * lds1[j00] + u01 * lds1[j01] + u10 * lds1[j10] + u11 * lds1[j11];
            v = (1.0f - frac) * v + frac * u;
        }
        res[c] = v;
        __syncthreads();
    }

    out[obase]                             = res[0];
    out[obase + (size_t)H_IMG * W_IMG]     = res[1];
    out[obase + (size_t)2 * H_IMG * W_IMG] = res[2];
}

// ------------------------------------------------------------------
extern "C" void kernel_launch(void* const* d_in, const int* in_sizes, int n_in,
                              void* d_out, int out_size, void* d_ws, size_t ws_size,
                              hipStream_t stream)
{
    const float* img      = (const float*)d_in[0];
    const float* features = (const float*)d_in[1];
    const float* lin_w    = (const float*)d_in[2];
    const float* lin_b    = (const float*)d_in[3];

    float* out        = (float*)d_out;
    float* gridOut    = out + OUT_OFF_GRID;
    float* out_matrix = out + OUT_OFF_MATRIX;
    float* out_affine = out + OUT_OFF_AFFINE;

    float* ws        = (float*)d_ws;
    float* ws_params = ws;
    float* pyr1 = ws + 1024;                              // 64*3*128*128
    float* pyr2 = pyr1 + (size_t)N_B * C_CH * 128 * 128;  // 64*3*64*64
    float* pyr3 = pyr2 + (size_t)N_B * C_CH * 64 * 64;    // 64*3*32*32

    params_kernel<<<N_B, 256, 0, stream>>>(features, lin_w, lin_b,
                                           out_matrix, out_affine, ws_params);

    // threads = NC * Hd * Wd/4 ; all divide exactly by 256
    int t1 = N_B * C_CH * 128 * 32;
    down_kernel<256, 256><<<t1 / 256, 256, 0, stream>>>(img,  pyr1);
    int t2 = N_B * C_CH * 64 * 16;
    down_kernel<128, 128><<<t2 / 256, 256, 0, stream>>>(pyr1, pyr2);
    int t3 = N_B * C_CH * 32 * 8;
    down_kernel<64, 64><<<t3 / 256, 256, 0, stream>>>(pyr2, pyr3);

    warp_kernel<<<dim3(H_IMG * W_IMG / 256, N_B), 256, 0, stream>>>(
        img, pyr1, pyr2, pyr3, ws_params, out, gridOut);
}

// Round 4
// 174.576 us; speedup vs baseline: 1.3256x; 1.3256x over previous
//
#include <hip/hip_runtime.h>
#include <math.h>

// Problem constants (N,C,H,W,D) = (64, 3, 256, 256, 512)
#define N_B 64
#define C_CH 3
#define H_IMG 256
#define W_IMG 256
#define D_FEAT 512

#define OUT_OFF_GRID   12582912
#define OUT_OFF_MATRIX 20971520
#define OUT_OFF_AFFINE 20971904

// ------------------------------------------------------------------
// Kernel 1: per-batch linear head -> affine matrix + level
// ------------------------------------------------------------------
__global__ void params_kernel(const float* __restrict__ features,
                              const float* __restrict__ lin_w,
                              const float* __restrict__ lin_b,
                              float* __restrict__ out_matrix,
                              float* __restrict__ out_affine,
                              float* __restrict__ ws_params)
{
    const int n = blockIdx.x;
    const int t = threadIdx.x;
    const float* f = features + n * D_FEAT;
    float f0 = f[t];
    float f1 = f[t + 256];
    float a0 = f0 * lin_w[0 * D_FEAT + t] + f1 * lin_w[0 * D_FEAT + t + 256];
    float a1 = f0 * lin_w[1 * D_FEAT + t] + f1 * lin_w[1 * D_FEAT + t + 256];
    float a2 = f0 * lin_w[2 * D_FEAT + t] + f1 * lin_w[2 * D_FEAT + t + 256];
    float a3 = f0 * lin_w[3 * D_FEAT + t] + f1 * lin_w[3 * D_FEAT + t + 256];

    __shared__ float red[4][256];
    red[0][t] = a0; red[1][t] = a1; red[2][t] = a2; red[3][t] = a3;
    __syncthreads();
    for (int s = 128; s > 0; s >>= 1) {
        if (t < s) {
            red[0][t] += red[0][t + s];
            red[1][t] += red[1][t + s];
            red[2][t] += red[2][t + s];
            red[3][t] += red[3][t + s];
        }
        __syncthreads();
    }
    if (t == 0) {
        float p0 = red[0][0] + lin_b[0];
        float p1 = red[1][0] + lin_b[1];
        float p2 = red[2][0] + lin_b[2];
        float p3 = red[3][0] + lin_b[3];
        float rot   = tanhf(p0) * 3.14159265358979323846f;
        float scale = expf(p1);
        float c = cosf(rot), s = sinf(rot);
        float m00 = scale * c, m01 = -scale * s, m02 = p2;
        float m10 = scale * s, m11 =  scale * c, m12 = p3;
        out_matrix[n * 6 + 0] = m00;
        out_matrix[n * 6 + 1] = m01;
        out_matrix[n * 6 + 2] = m02;
        out_matrix[n * 6 + 3] = m10;
        out_matrix[n * 6 + 4] = m11;
        out_matrix[n * 6 + 5] = m12;
        out_affine[n * 4 + 0] = rot;
        out_affine[n * 4 + 1] = scale;
        out_affine[n * 4 + 2] = p2;
        out_affine[n * 4 + 3] = p3;
        // affine grid => Jacobian norm is exactly `scale` in both directions
        float lv = log2f(fmaxf(scale, 1.0f));
        lv = fminf(fmaxf(lv, 0.0f), 2.5f);
        ws_params[n * 8 + 0] = m00;
        ws_params[n * 8 + 1] = m01;
        ws_params[n * 8 + 2] = m02;
        ws_params[n * 8 + 3] = m10;
        ws_params[n * 8 + 4] = m11;
        ws_params[n * 8 + 5] = m12;
        ws_params[n * 8 + 6] = lv;
        ws_params[n * 8 + 7] = 0.0f;
    }
}

// ------------------------------------------------------------------
// Kernel 2: depthwise 4x4 binomial blur, reflect (1,2), stride 2.
// 4 outputs per thread: 2 aligned float4 + 2 scalars per source row.
// ------------------------------------------------------------------
template<int Hs, int Ws>
__global__ void down_kernel(const float* __restrict__ src, float* __restrict__ dst)
{
    constexpr int Hd = Hs / 2, Wd = Ws / 2;
    constexpr int QUADS = Wd / 4;

    const int idx = blockIdx.x * blockDim.x + threadIdx.x;
    const int t   = idx & (QUADS - 1);
    const int i   = (idx / QUADS) & (Hd - 1);
    const int nc  = idx / (QUADS * Hd);

    const float* __restrict__ s = src + (size_t)nc * Hs * Ws;

    int r[4];
#pragma unroll
    for (int a = 0; a < 4; a++) {
        int q = 2 * i + a - 1;
        if (q < 0) q = -q;
        if (q >= Hs) q = 2 * Hs - 2 - q;
        r[a] = q;
    }
    const int c8 = 8 * t;
    const int li = (t > 0)         ? c8 - 1 : 1;       // reflect -1 -> 1
    const int ri = (t < QUADS - 1) ? c8 + 8 : Ws - 2;  // reflect Ws -> Ws-2

    const float k0 = 0.125f, k1 = 0.375f;
    const float kr[4] = {0.125f, 0.375f, 0.375f, 0.125f};

    float acc0 = 0.f, acc1 = 0.f, acc2 = 0.f, acc3 = 0.f;
#pragma unroll
    for (int a = 0; a < 4; a++) {
        const float* row = s + (size_t)r[a] * Ws;
        float4 A = *(const float4*)(row + c8);
        float4 B = *(const float4*)(row + c8 + 4);
        float L = row[li];
        float R = row[ri];
        float h0 = k0 * L   + k1 * A.x + k1 * A.y + k0 * A.z;
        float h1 = k0 * A.y + k1 * A.z + k1 * A.w + k0 * B.x;
        float h2 = k0 * A.w + k1 * B.x + k1 * B.y + k0 * B.z;
        float h3 = k0 * B.y + k1 * B.z + k1 * B.w + k0 * R;
        acc0 += kr[a] * h0;
        acc1 += kr[a] * h1;
        acc2 += kr[a] * h2;
        acc3 += kr[a] * h3;
    }
    float4* d4 = (float4*)(dst + (size_t)nc * Hd * Wd + (size_t)i * Wd + 4 * t);
    *d4 = make_float4(acc0, acc1, acc2, acc3);
}

// ------------------------------------------------------------------
// Kernel 3: affine grid + mipmap bilinear warp.
// 16x4 wave tiles; x-tap pairs fetched as one (unaligned-ok) float2.
// ------------------------------------------------------------------
__device__ __forceinline__ const float* lvl_ptr(int l, const float* img,
                                                const float* p1, const float* p2,
                                                const float* p3)
{
    return (l == 0) ? img : ((l == 1) ? p1 : ((l == 2) ? p2 : p3));
}

// bilinear sample of 3 channels at level l using paired x-loads
__device__ __forceinline__ void sample_level_pair(const float* __restrict__ p, int n, int l,
                                                  float X, float Y, float out[3])
{
    const int Wl = W_IMG >> l;
    const int Hl = H_IMG >> l;
    float x = (X + 1.0f) * (0.5f * (float)Wl) - 0.5f;
    float y = (Y + 1.0f) * (0.5f * (float)Hl) - 0.5f;
    float x0f = floorf(x), y0f = floorf(y);
    float tx = x - x0f, ty = y - y0f;
    int x0 = (int)x0f, y0 = (int)y0f;
    int y0i = min(max(y0,     0), Hl - 1);
    int y1i = min(max(y0 + 1, 0), Hl - 1);
    // pair base column: clamp so [xp, xp+1] is always in range
    int xp = min(max(x0, 0), Wl - 2);
    // tap selection under border clamp:
    //  x0 <  0      -> x0i = x1i = 0      = pair.x  (xp = 0)
    //  x0 >= Wl-1   -> x0i = x1i = Wl-1   = pair.y  (xp = Wl-2)
    //  else         -> x0i = xp (pair.x), x1i = xp+1 (pair.y)
    const bool selHi0 = (x0 >= Wl - 1);   // tap0 takes .y
    const bool selLo1 = (x0 < 0);         // tap1 takes .x
    float w00 = (1.0f - tx) * (1.0f - ty);
    float w01 = tx * (1.0f - ty);
    float w10 = (1.0f - tx) * ty;
    float w11 = tx * ty;
    const float* base = p + (size_t)n * C_CH * Hl * Wl;
#pragma unroll
    for (int c = 0; c < C_CH; c++) {
        const float* pc = base + (size_t)c * Hl * Wl;
        float2 a = *(const float2*)(pc + y0i * Wl + xp);   // HW tolerates 4B align
        float2 b = *(const float2*)(pc + y1i * Wl + xp);
        float t00 = selHi0 ? a.y : a.x;
        float t01 = selLo1 ? a.x : a.y;
        float t10 = selHi0 ? b.y : b.x;
        float t11 = selLo1 ? b.x : b.y;
        out[c] = w00 * t00 + w01 * t01 + w10 * t10 + w11 * t11;
    }
}

__global__ void warp_kernel(const float* __restrict__ img,
                            const float* __restrict__ pyr1,
                            const float* __restrict__ pyr2,
                            const float* __restrict__ pyr3,
                            const float* __restrict__ ws_params,
                            float* __restrict__ out,
                            float* __restrict__ gridOut)
{
    const int n = blockIdx.y;
    const int tile = blockIdx.x;
    const int tid = threadIdx.x;
    // block covers 32x8; each 64-lane wave covers a 16x4 sub-tile
    const int w0 = (tile & 7) << 5;
    const int h0 = (tile >> 3) << 3;
    const int w = w0 + (((tid >> 6) & 1) << 4) + (tid & 15);
    const int h = h0 + ((tid >> 7) << 2) + ((tid >> 4) & 3);

    const float* P = ws_params + n * 8;
    float m00 = P[0], m01 = P[1], m02 = P[2];
    float m10 = P[3], m11 = P[4], m12 = P[5];
    float lv  = P[6];

    float gx = ((float)w + 0.5f) * (2.0f / (float)W_IMG) - 1.0f;
    float gy = ((float)h + 0.5f) * (2.0f / (float)H_IMG) - 1.0f;
    float X = m00 * gx + m01 * gy + m02;
    float Y = m10 * gx + m11 * gy + m12;

    // grid output (N,H,W,2) — never re-read: non-temporal
    float2* g2 = (float2*)gridOut + ((size_t)(n * H_IMG + h) * W_IMG + w);
    __builtin_nontemporal_store(X, &g2->x);
    __builtin_nontemporal_store(Y, &g2->y);

    int   l0   = (int)lv;          // lv in [0, 2.5]: trunc == floor
    float frac = lv - (float)l0;

    float c0[3];
    sample_level_pair(lvl_ptr(l0, img, pyr1, pyr2, pyr3), n, l0, X, Y, c0);

    float r0, r1, r2;
    if (frac > 0.0f) {             // wave-uniform (one n per block)
        float c1[3];
        sample_level_pair(lvl_ptr(l0 + 1, img, pyr1, pyr2, pyr3), n, l0 + 1, X, Y, c1);
        float wA = 1.0f - frac;
        r0 = wA * c0[0] + frac * c1[0];
        r1 = wA * c0[1] + frac * c1[1];
        r2 = wA * c0[2] + frac * c1[2];
    } else {
        r0 = c0[0]; r1 = c0[1]; r2 = c0[2];
    }

    size_t base = ((size_t)n * C_CH * H_IMG + h) * W_IMG + w;
    __builtin_nontemporal_store(r0, out + base);
    __builtin_nontemporal_store(r1, out + base + (size_t)H_IMG * W_IMG);
    __builtin_nontemporal_store(r2, out + base + (size_t)2 * H_IMG * W_IMG);
}

// ------------------------------------------------------------------
extern "C" void kernel_launch(void* const* d_in, const int* in_sizes, int n_in,
                              void* d_out, int out_size, void* d_ws, size_t ws_size,
                              hipStream_t stream)
{
    const float* img      = (const float*)d_in[0];
    const float* features = (const float*)d_in[1];
    const float* lin_w    = (const float*)d_in[2];
    const float* lin_b    = (const float*)d_in[3];

    float* out        = (float*)d_out;
    float* gridOut    = out + OUT_OFF_GRID;
    float* out_matrix = out + OUT_OFF_MATRIX;
    float* out_affine = out + OUT_OFF_AFFINE;

    float* ws        = (float*)d_ws;
    float* ws_params = ws;
    float* pyr1 = ws + 1024;                              // 64*3*128*128
    float* pyr2 = pyr1 + (size_t)N_B * C_CH * 128 * 128;  // 64*3*64*64
    float* pyr3 = pyr2 + (size_t)N_B * C_CH * 64 * 64;    // 64*3*32*32

    params_kernel<<<N_B, 256, 0, stream>>>(features, lin_w, lin_b,
                                           out_matrix, out_affine, ws_params);

    int t1 = N_B * C_CH * 128 * 32;
    down_kernel<256, 256><<<t1 / 256, 256, 0, stream>>>(img,  pyr1);
    int t2 = N_B * C_CH * 64 * 16;
    down_kernel<128, 128><<<t2 / 256, 256, 0, stream>>>(pyr1, pyr2);
    int t3 = N_B * C_CH * 32 * 8;
    down_kernel<64, 64><<<t3 / 256, 256, 0, stream>>>(pyr2, pyr3);

    warp_kernel<<<dim3(H_IMG * W_IMG / 256, N_B), 256, 0, stream>>>(
        img, pyr1, pyr2, pyr3, ws_params, out, gridOut);
}